// Round 4
// baseline (374.052 us; speedup 1.0000x reference)
//
#include <hip/hip_runtime.h>

#define K_CODES 4096
#define DIM 256
#define SEQ 2048
#define NTOK 65536

typedef __bf16 bf16x8 __attribute__((ext_vector_type(8)));
typedef float floatx4 __attribute__((ext_vector_type(4)));
typedef unsigned short u16x8 __attribute__((ext_vector_type(8)));

__device__ __forceinline__ unsigned short f2bf(float f) {
    union { float f; unsigned int u; } v; v.f = f;
    unsigned int u = v.u;
    unsigned int r = u + 0x7fffu + ((u >> 16) & 1u);   // RNE
    return (unsigned short)(r >> 16);
}

// ---------------- kernel 1: swizzled bf16 codebook + biased norms -----------
// cb_swz[((gc*16 + ns*8 + ks)*64 + quad*16 + col)*8 + j]
//   = bf16(codebook[gc*32 + ns*16 + col][quad*8 + ks*32 + j])
// norms[row] = ||e||^2 + 1.0  (bias keeps dist positive for uint-packed argmin)
__global__ __launch_bounds__(256) void k_prep(const float* __restrict__ cb,
        unsigned short* __restrict__ cb_swz, float* __restrict__ norms,
        float* __restrict__ loss_slot) {
    const int c = blockIdx.x;
    const int t = threadIdx.x;
    const int row_loc = t >> 3;       // 0..31 code within chunk
    const int ks = t & 7;             // k-slice
    const int row = c * 32 + row_loc;
    const float* src = cb + (size_t)row * DIM + ks * 32;
    float vals[32];
    float s = 0.0f;
    #pragma unroll
    for (int i = 0; i < 8; ++i) {
        floatx4 v = *(const floatx4*)(src + i * 4);
        #pragma unroll
        for (int j = 0; j < 4; ++j) { vals[i * 4 + j] = v[j]; s += v[j] * v[j]; }
    }
    const int ns = row_loc >> 4, col = row_loc & 15;
    #pragma unroll
    for (int quad = 0; quad < 4; ++quad) {
        u16x8 p;
        #pragma unroll
        for (int j = 0; j < 8; ++j) p[j] = f2bf(vals[quad * 8 + j]);
        *(u16x8*)(cb_swz + ((size_t)((c * 16 + ns * 8 + ks) * 64 + quad * 16 + col)) * 8) = p;
    }
    s += __shfl_xor(s, 1); s += __shfl_xor(s, 2); s += __shfl_xor(s, 4);
    if (ks == 0) norms[row] = s + 1.0f;
    if (c == 0 && t == 0) *loss_slot = 0.0f;
}

// ---------------- kernel 2: fused argmin + gather + loss --------------------
// Block: 128 thr = 2 waves, 64 tokens. Wave w scans code half h=w (2048 codes)
// with register ping-pong prefetch of B fragments. Merge via LDS; loss computed
// algebraically (no X re-read); epilogue gathers cb rows -> transposed stores.
__global__ __launch_bounds__(128, 2) void k_main(const float* __restrict__ x,
        const unsigned short* __restrict__ cb_swz, const float* __restrict__ norms,
        const float* __restrict__ cb, float* __restrict__ out,
        float* __restrict__ loss_slot) {
    __shared__ __align__(16) unsigned short xs[2][8448];  // 33792 B
    __shared__ __align__(16) float qs[16 * 260];          // 16640 B
    __shared__ unsigned int mkey[2][64];
    __shared__ float sumx2s[64];
    __shared__ int sidx[64];

    const int t = threadIdx.x;
    const int lane = t & 63, w = t >> 6;
    const int col = lane & 15, quad = lane >> 4;
    const int h = w;                       // code half for this wave
    const int tok0 = blockIdx.x * 64;
    const int b = tok0 >> 11, s0 = tok0 & 2047;
    const float* xin = x + (size_t)b * DIM * SEQ;

    // ---- stage sub w (32 tokens) as -2x bf16; accumulate fp32 sum(x^2)
    const int dl = lane >> 3, so = (lane & 7) * 4;
    {
        const int sbase = s0 + w * 32;
        floatx4 a2 = {0.0f, 0.0f, 0.0f, 0.0f};
        for (int i = 0; i < 32; ++i) {
            int d = i * 8 + dl;
            floatx4 v = *(const floatx4*)(xin + (size_t)d * SEQ + sbase + so);
            a2 += v * v;
            #pragma unroll
            for (int j = 0; j < 4; ++j) xs[w][(so + j) * 264 + d] = f2bf(-2.0f * v[j]);
        }
        #pragma unroll
        for (int off = 8; off <= 32; off <<= 1)
            #pragma unroll
            for (int j = 0; j < 4; ++j) a2[j] += __shfl_xor(a2[j], off);
        if (dl == 0)
            #pragma unroll
            for (int j = 0; j < 4; ++j) sumx2s[w * 32 + (lane & 7) * 4 + j] = a2[j];
    }
    __syncthreads();

    // ---- A fragments for all 64 tokens (both waves identical)
    bf16x8 af[4][8];
    #pragma unroll
    for (int sub = 0; sub < 2; ++sub)
        #pragma unroll
        for (int m2 = 0; m2 < 2; ++m2)
            #pragma unroll
            for (int ks = 0; ks < 8; ++ks)
                af[sub * 2 + m2][ks] =
                    *(const bf16x8*)&xs[sub][(m2 * 16 + col) * 264 + quad * 8 + ks * 32];

    unsigned int minkey[4][4];
    #pragma unroll
    for (int m = 0; m < 4; ++m)
        #pragma unroll
        for (int r = 0; r < 4; ++r) minkey[m][r] = 0xFFFFFFFFu;

    // it = 0..127 half-chunks of 16 codes; elem offset = (h*1024 + it*8 + ks)*512 + lane*8
    const unsigned short* cbb = cb_swz + (size_t)h * 1024 * 512 + lane * 8;

    auto ldb = [&](bf16x8* dst, int it) {
        const unsigned short* p = cbb + (size_t)it * 8 * 512;
        #pragma unroll
        for (int ks = 0; ks < 8; ++ks) dst[ks] = *(const bf16x8*)(p + ks * 512);
    };
    auto compute = [&](const bf16x8* buf, float nv, int it) {
        floatx4 acc[4];
        #pragma unroll
        for (int m = 0; m < 4; ++m) acc[m] = (floatx4){nv, nv, nv, nv};
        #pragma unroll
        for (int ks = 0; ks < 8; ++ks)
            #pragma unroll
            for (int m = 0; m < 4; ++m)
                acc[m] = __builtin_amdgcn_mfma_f32_16x16x32_bf16(
                             af[m][ks], buf[ks], acc[m], 0, 0, 0);
        const unsigned int code = (unsigned int)(h * 2048 + it * 16 + col);
        #pragma unroll
        for (int m = 0; m < 4; ++m)
            #pragma unroll
            for (int r = 0; r < 4; ++r) {
                unsigned int key = (__float_as_uint(acc[m][r]) & 0xFFFFF000u) | code;
                minkey[m][r] = key < minkey[m][r] ? key : minkey[m][r];
            }
    };

    bf16x8 bA[8], bB[8];
    float nvA = norms[h * 2048 + col], nvB;
    ldb(bA, 0);
    for (int c = 0; c < 64; ++c) {
        const int it = c * 2;
        nvB = norms[h * 2048 + (it + 1) * 16 + col];
        ldb(bB, it + 1);                       // prefetch while computing bA
        compute(bA, nvA, it);
        const int itn = (it + 2) & 127;        // wrap: last prefetch harmlessly reloads it=0
        nvA = norms[h * 2048 + itn * 16 + col];
        ldb(bA, itn);                          // prefetch while computing bB
        compute(bB, nvB, it + 1);
    }

    // ---- per-wave column reduce -> LDS
    #pragma unroll
    for (int m = 0; m < 4; ++m)
        #pragma unroll
        for (int r = 0; r < 4; ++r) {
            unsigned int k = minkey[m][r];
            #pragma unroll
            for (int off = 8; off >= 1; off >>= 1) {
                unsigned int o = __shfl_xor(k, off);
                k = o < k ? o : k;
            }
            if (col == 0) mkey[w][m * 16 + quad * 4 + r] = k;
        }
    __syncthreads();

    // ---- merge halves, loss, indices (wave 0)
    if (t < 64) {
        unsigned int k0 = mkey[0][t], k1 = mkey[1][t];
        unsigned int km = k0 < k1 ? k0 : k1;
        sidx[t] = (int)(km & 0xFFFu);
        float dtok = __uint_as_float(km & 0xFFFFF000u) - 1.0f + sumx2s[t];
        #pragma unroll
        for (int off = 32; off; off >>= 1) dtok += __shfl_xor(dtok, off);
        if (t == 0) atomicAdd(loss_slot, dtok * (1.25f / 16777216.0f));
    }

    // ---- gather + transpose + store out (4 passes x 16 tokens)
    for (int pass = 0; pass < 4; ++pass) {
        __syncthreads();
        {
            const int tl = t >> 3, seg = t & 7;
            const float* src = cb + (size_t)sidx[pass * 16 + tl] * DIM + seg * 32;
            #pragma unroll
            for (int i = 0; i < 8; ++i)
                *(floatx4*)&qs[tl * 260 + seg * 32 + i * 4] = *(const floatx4*)(src + i * 4);
        }
        __syncthreads();
        {
            const int d0 = t >> 2, a = t & 3;
            #pragma unroll
            for (int p = 0; p < 8; ++p) {
                const int d = p * 32 + d0;
                floatx4 q;
                #pragma unroll
                for (int j = 0; j < 4; ++j) q[j] = qs[(a * 4 + j) * 260 + d];
                *(floatx4*)(out + (size_t)b * DIM * SEQ + (size_t)d * SEQ
                            + s0 + pass * 16 + a * 4) = q;
            }
        }
    }
}

extern "C" void kernel_launch(void* const* d_in, const int* in_sizes, int n_in,
                              void* d_out, int out_size, void* d_ws, size_t ws_size,
                              hipStream_t stream) {
    const float* inputs   = (const float*)d_in[0];
    const float* codebook = (const float*)d_in[1];
    float* out = (float*)d_out;
    unsigned short* cb_swz = (unsigned short*)d_ws;                                  // 2 MB
    float* norms = (float*)((char*)d_ws + (size_t)K_CODES * DIM * 2);                // 16 KB
    float* loss_slot = out + (out_size - 1);

    hipLaunchKernelGGL(k_prep, dim3(K_CODES / 32), dim3(256), 0, stream,
                       codebook, cb_swz, norms, loss_slot);
    hipLaunchKernelGGL(k_main, dim3(NTOK / 64), dim3(128), 0, stream,
                       inputs, cb_swz, norms, codebook, out, loss_slot);
}

// Round 5
// 261.977 us; speedup vs baseline: 1.4278x; 1.4278x over previous
//
#include <hip/hip_runtime.h>

#define K_CODES 4096
#define DIM 256
#define SEQ 2048
#define NTOK 65536

typedef __bf16 bf16x8 __attribute__((ext_vector_type(8)));
typedef float floatx4 __attribute__((ext_vector_type(4)));
typedef unsigned short u16x8 __attribute__((ext_vector_type(8)));

__device__ __forceinline__ unsigned short f2bf(float f) {
    union { float f; unsigned int u; } v; v.f = f;
    unsigned int u = v.u;
    unsigned int r = u + 0x7fffu + ((u >> 16) & 1u);   // RNE
    return (unsigned short)(r >> 16);
}

// async global->LDS, 16B per lane. LDS dest = wave-uniform base + lane*16.
__device__ __forceinline__ void async_cp16(const void* g, const void* lds_base) {
    typedef __attribute__((address_space(1))) const unsigned int guint;
    typedef __attribute__((address_space(3))) unsigned int luint;
    __builtin_amdgcn_global_load_lds(
        (guint*)(unsigned long long)g,
        (luint*)(unsigned int)(unsigned long long)lds_base,
        16, 0, 0);
}

// ---------------- kernel 1: swizzled bf16 codebook + biased norms -----------
// cb_swz[((gc*16 + ns*8 + ks)*64 + quad*16 + col)*8 + j]
//   = bf16(codebook[gc*32 + ns*16 + col][quad*8 + ks*32 + j])
// norms[row] = ||e||^2 + 0.25 (bias keeps dist positive; exp ~ -2 -> key
// truncation quantum 2^-13..2^-14, well under the 2.2e-3 code-distance std)
__global__ __launch_bounds__(256) void k_prep(const float* __restrict__ cb,
        unsigned short* __restrict__ cb_swz, float* __restrict__ norms,
        float* __restrict__ loss_slot) {
    const int c = blockIdx.x;
    const int t = threadIdx.x;
    const int row_loc = t >> 3;       // 0..31 code within chunk
    const int ks = t & 7;             // k-slice
    const int row = c * 32 + row_loc;
    const float* src = cb + (size_t)row * DIM + ks * 32;
    float vals[32];
    float s = 0.0f;
    #pragma unroll
    for (int i = 0; i < 8; ++i) {
        floatx4 v = *(const floatx4*)(src + i * 4);
        #pragma unroll
        for (int j = 0; j < 4; ++j) { vals[i * 4 + j] = v[j]; s += v[j] * v[j]; }
    }
    const int ns = row_loc >> 4, col = row_loc & 15;
    #pragma unroll
    for (int quad = 0; quad < 4; ++quad) {
        u16x8 p;
        #pragma unroll
        for (int j = 0; j < 8; ++j) p[j] = f2bf(vals[quad * 8 + j]);
        *(u16x8*)(cb_swz + ((size_t)((c * 16 + ns * 8 + ks) * 64 + quad * 16 + col)) * 8) = p;
    }
    s += __shfl_xor(s, 1); s += __shfl_xor(s, 2); s += __shfl_xor(s, 4);
    if (ks == 0) norms[row] = s + 0.25f;
    if (c == 0 && t == 0) *loss_slot = 0.0f;
}

// ---------------- kernel 2: MFMA distance GEMM + packed argmin --------------
// 256 thr = 4 waves, 256 tokens/block (64/wave, m=4). Codes split in halves:
// grid 512 = 2 blocks/CU co-resident. B staged once per block into a
// conflict-free LDS ring via global_load_lds -> 4-way cross-wave reuse
// (L2 traffic 4x lower than per-wave streaming).
__global__ __launch_bounds__(256, 2) void k_argmin(const float* __restrict__ x,
        const unsigned short* __restrict__ cb_swz, const float* __restrict__ norms,
        unsigned int* __restrict__ halfmin, float* __restrict__ loss_slot) {
    __shared__ __align__(16) unsigned short xs[64 * 264];    // 33792 B: X stage
    __shared__ __align__(16) unsigned short ring[2][8192];   // 32768 B: B ring
    __shared__ float wpart[4];
    const int t = threadIdx.x;
    const int lane = t & 63, w = t >> 6;
    const int col = lane & 15, quad = lane >> 4;
    const int bx = blockIdx.x;
    const int h = bx & 1;                  // code half
    const int tb = (bx >> 1) * 256;        // first token of block
    const int b = tb >> 11, s0 = tb & 2047;
    const float* xin = x + (size_t)b * DIM * SEQ;

    // prefetch B chunk 0 of this half into ring[0] (overlaps X staging)
    {
        const char* src = (const char*)cb_swz + (size_t)h * 64 * 16384;
        #pragma unroll
        for (int i = 0; i < 4; ++i)
            async_cp16(src + i * 4096 + w * 1024 + lane * 16,
                       (char*)ring[0] + i * 4096 + w * 1024);
    }

    // ---- X staging: 4 phases x 64 tokens; wave ph grabs its A fragments.
    // Also accumulate ||x||^2 over the whole block (for algebraic loss).
    bf16x8 af[4][8];
    float a2 = 0.0f;
    const int dg = t >> 4, sq = (t & 15) * 4;
    for (int ph = 0; ph < 4; ++ph) {
        const int sbase = s0 + ph * 64 + sq;
        for (int i = 0; i < 16; ++i) {
            int d = i * 16 + dg;
            floatx4 v = *(const floatx4*)(xin + (size_t)d * SEQ + sbase);
            a2 += v[0]*v[0] + v[1]*v[1] + v[2]*v[2] + v[3]*v[3];
            #pragma unroll
            for (int j = 0; j < 4; ++j) xs[(sq + j) * 264 + d] = f2bf(-2.0f * v[j]);
        }
        __syncthreads();
        if (w == ph) {
            #pragma unroll
            for (int m = 0; m < 4; ++m)
                #pragma unroll
                for (int ks = 0; ks < 8; ++ks)
                    af[m][ks] = *(const bf16x8*)&xs[(m * 16 + col) * 264
                                                    + quad * 8 + ks * 32];
        }
        __syncthreads();
    }
    // block-reduce a2; h==0 blocks contribute ||x||^2 part of the loss
    #pragma unroll
    for (int off = 1; off < 64; off <<= 1) a2 += __shfl_xor(a2, off);
    if (lane == 0) wpart[w] = a2;
    __syncthreads();
    if (t == 0 && h == 0)
        atomicAdd(loss_slot,
                  (wpart[0] + wpart[1] + wpart[2] + wpart[3]) * (1.25f / 16777216.0f));

    unsigned int minkey[4][4];
    #pragma unroll
    for (int m = 0; m < 4; ++m)
        #pragma unroll
        for (int r = 0; r < 4; ++r) minkey[m][r] = 0xFFFFFFFFu;

    #pragma unroll 1
    for (int c = 0; c < 64; ++c) {
        __syncthreads();                       // ring[c&1] ready, readers of c-1 done
        if (c < 63) {
            const char* src = (const char*)cb_swz + (size_t)(h * 64 + c + 1) * 16384;
            char* dst = (char*)ring[(c + 1) & 1];
            #pragma unroll
            for (int i = 0; i < 4; ++i)
                async_cp16(src + i * 4096 + w * 1024 + lane * 16,
                           dst + i * 4096 + w * 1024);
        }
        const unsigned short* buf = ring[c & 1];
        #pragma unroll
        for (int ns = 0; ns < 2; ++ns) {
            const float nv = norms[(h * 64 + c) * 32 + ns * 16 + col];
            bf16x8 bfrag[8];
            #pragma unroll
            for (int ks = 0; ks < 8; ++ks)     // lane-contiguous 1KB: conflict-free
                bfrag[ks] = *(const bf16x8*)&buf[((ns * 8 + ks) * 64 + lane) * 8];
            floatx4 acc[4];
            #pragma unroll
            for (int m = 0; m < 4; ++m) acc[m] = (floatx4){nv, nv, nv, nv};
            #pragma unroll
            for (int ks = 0; ks < 8; ++ks)
                #pragma unroll
                for (int m = 0; m < 4; ++m)
                    acc[m] = __builtin_amdgcn_mfma_f32_16x16x32_bf16(
                                 af[m][ks], bfrag[ks], acc[m], 0, 0, 0);
            const unsigned int code = (unsigned int)((h * 64 + c) * 32 + ns * 16 + col);
            #pragma unroll
            for (int m = 0; m < 4; ++m)
                #pragma unroll
                for (int r = 0; r < 4; ++r) {
                    unsigned int key = (__float_as_uint(acc[m][r]) & 0xFFFFF000u) | code;
                    minkey[m][r] = key < minkey[m][r] ? key : minkey[m][r];
                }
        }
    }

    // ---- min over 16 column-lanes, write packed (dist|code) per token
    #pragma unroll
    for (int m = 0; m < 4; ++m)
        #pragma unroll
        for (int r = 0; r < 4; ++r) {
            unsigned int k = minkey[m][r];
            #pragma unroll
            for (int off = 8; off >= 1; off >>= 1) {
                unsigned int o = __shfl_xor(k, off);
                k = o < k ? o : k;
            }
            if (col == 0)
                halfmin[h * NTOK + tb + w * 64 + m * 16 + quad * 4 + r] = k;
        }
}

// ---------------- kernel 3: merge + gather (no x re-read) + loss ------------
// 256 thr, 64 tokens/block. Direct gather: thread (q=t&15) owns tokens q*4..+3,
// reads 4 cb scalars per d-step, stores coalesced 256B rows. Loss = sum of
// unpacked min distances (||x||^2 part added by k_argmin).
__global__ __launch_bounds__(256) void k_gather(const float* __restrict__ cb,
        const unsigned int* __restrict__ halfmin, float* __restrict__ out,
        float* __restrict__ loss_slot) {
    __shared__ int sidx[64];
    const int t = threadIdx.x;
    const int tb = blockIdx.x * 64;
    const int b = tb >> 11, s0 = tb & 2047;
    if (t < 64) {
        unsigned int k0 = halfmin[tb + t], k1 = halfmin[NTOK + tb + t];
        unsigned int km = k0 < k1 ? k0 : k1;
        sidx[t] = (int)(km & 0xFFFu);
        float dv = __uint_as_float(km & 0xFFFFF000u) - 0.25f;
        #pragma unroll
        for (int off = 32; off; off >>= 1) dv += __shfl_xor(dv, off);
        if (t == 0) atomicAdd(loss_slot, dv * (1.25f / 16777216.0f));
    }
    __syncthreads();
    const int q = t & 15, dg = t >> 4;
    int rows[4];
    #pragma unroll
    for (int k = 0; k < 4; ++k) rows[k] = sidx[q * 4 + k];
    #pragma unroll
    for (int i = 0; i < 16; ++i) {
        const int d = i * 16 + dg;
        floatx4 v;
        #pragma unroll
        for (int k = 0; k < 4; ++k) v[k] = cb[(size_t)rows[k] * DIM + d];
        *(floatx4*)(out + (size_t)b * DIM * SEQ + (size_t)d * SEQ + s0 + q * 4) = v;
    }
}

extern "C" void kernel_launch(void* const* d_in, const int* in_sizes, int n_in,
                              void* d_out, int out_size, void* d_ws, size_t ws_size,
                              hipStream_t stream) {
    const float* inputs   = (const float*)d_in[0];
    const float* codebook = (const float*)d_in[1];
    float* out = (float*)d_out;
    unsigned short* cb_swz = (unsigned short*)d_ws;                                  // 2 MB
    float* norms = (float*)((char*)d_ws + (size_t)K_CODES * DIM * 2);                // 16 KB
    unsigned int* halfmin = (unsigned int*)((char*)d_ws + (size_t)K_CODES * DIM * 2
                                            + K_CODES * 4);                          // 512 KB
    float* loss_slot = out + (out_size - 1);

    hipLaunchKernelGGL(k_prep,   dim3(K_CODES / 32),     dim3(256), 0, stream,
                       codebook, cb_swz, norms, loss_slot);
    hipLaunchKernelGGL(k_argmin, dim3(NTOK / 256 * 2),   dim3(256), 0, stream,
                       inputs, cb_swz, norms, halfmin, loss_slot);
    hipLaunchKernelGGL(k_gather, dim3(NTOK / 64),        dim3(256), 0, stream,
                       codebook, halfmin, out, loss_slot);
}